// Round 1
// baseline (5201.931 us; speedup 1.0000x reference)
//
#include <hip/hip_runtime.h>
#include <hip/hip_bf16.h>
#include <stdint.h>

// Problem constants
#define B_   2
#define S_   4096
#define H_   512
#define G_   18
#define NH_  8
#define D_   64
#define M_   (B_ * S_)      // 8192 tokens
#define KBIG (G_ * H_)      // 9216  (GEMM K)
#define NBIG (2 * KBIG)     // 18432 (GEMM N: key cols | value cols)

typedef unsigned short ushort_t;
typedef __attribute__((ext_vector_type(8))) short short8;   // 8 bf16 (4 VGPRs)
typedef __attribute__((ext_vector_type(4))) float f32x4;

__device__ __forceinline__ ushort_t f2bf(float f) {
    union { float f; uint32_t u; } v; v.f = f;
    uint32_t u = v.u;
    uint32_t r = (u + 0x7FFFu + ((u >> 16) & 1u)) >> 16;    // RNE
    return (ushort_t)r;
}
__device__ __forceinline__ float bf2f(ushort_t u) {
    union { uint32_t u; float f; } v; v.u = ((uint32_t)u) << 16;
    return v.f;
}

__device__ __forceinline__ void gload_lds16(const ushort_t* g, ushort_t* l) {
    __builtin_amdgcn_global_load_lds(
        (const __attribute__((address_space(1))) void*)g,
        (__attribute__((address_space(3))) void*)l,
        16, 0, 0);
}

// ---------------------------------------------------------------------------
// Transpose + f32->bf16: src [K][N] f32 row-major  ->  dst [N][K] bf16 row-major
// 64x64 tiles, 256 threads. LDS pad 66 -> conflict-free transposed read.
// ---------------------------------------------------------------------------
__global__ __launch_bounds__(256) void transpose_f32_to_bf16(
    const float* __restrict__ src, ushort_t* __restrict__ dst, int K, int N)
{
    __shared__ ushort_t tile[64][66];
    const int k0 = blockIdx.y * 64;
    const int n0 = blockIdx.x * 64;
    const int t  = threadIdx.x;
    const int c  = t & 63;
    const int r0 = t >> 6;              // 0..3
#pragma unroll
    for (int p = 0; p < 16; ++p) {
        int r = p * 4 + r0;
        tile[r][c] = f2bf(src[(size_t)(k0 + r) * N + (n0 + c)]);
    }
    __syncthreads();
#pragma unroll
    for (int p = 0; p < 16; ++p) {
        int r = p * 4 + r0;
        dst[(size_t)(n0 + r) * K + (k0 + c)] = tile[c][r];
    }
}

// ---------------------------------------------------------------------------
// Plain f32 -> bf16 convert (vectorized x4)
// ---------------------------------------------------------------------------
__global__ __launch_bounds__(256) void convert_f32_bf16(
    const float* __restrict__ src, ushort_t* __restrict__ dst, int n4)
{
    int i = blockIdx.x * 256 + threadIdx.x;
    if (i >= n4) return;
    float4 v = ((const float4*)src)[i];
    ushort4 o;
    o.x = f2bf(v.x); o.y = f2bf(v.y); o.z = f2bf(v.z); o.w = f2bf(v.w);
    ((ushort4*)dst)[i] = o;
}

// ---------------------------------------------------------------------------
// Build gathered A matrix: A[m][g*512+h] = bf16( conn==-1 ? 0 : hs[b][clip(idx)][h] )
// One block per (g, m); 256 threads x 2 elems.
// ---------------------------------------------------------------------------
__global__ __launch_bounds__(256) void build_A(
    const float* __restrict__ hs, const int* __restrict__ conn,
    ushort_t* __restrict__ A)
{
    const int g = blockIdx.x;
    const int m = blockIdx.y;
    const int b = m >> 12;                          // m / 4096
    const int t = threadIdx.x;
    const int c = conn[(size_t)m * G_ + g];
    const size_t dst = (size_t)m * KBIG + (size_t)g * H_;
    if (c == -1) {
        ushort2 z; z.x = 0; z.y = 0;
        *(ushort2*)(A + dst + 2 * t) = z;
        return;
    }
    int tok = min(max(c, 0), S_ - 1);
    const float* src = hs + ((size_t)b * S_ + tok) * H_;
    float2 v = *(const float2*)(src + 2 * t);
    ushort2 o; o.x = f2bf(v.x); o.y = f2bf(v.y);
    *(ushort2*)(A + dst + 2 * t) = o;
}

// ---------------------------------------------------------------------------
// bf16 MFMA GEMM (m97 structure): C[M][N] = A[M][K] * Bt[N][K]^T
// 128x128 tile, BK=64, 256 threads = 4 waves (2x2), each wave 64x64 (4x4 frags
// of 16x16x32). Single-buffered LDS staged via global_load_lds width=16.
// Requires M%128==0, N%128==0, K%64==0.
// ---------------------------------------------------------------------------
template<int OUT_BF16>
__global__ __launch_bounds__(256) void gemm_bf16_nt(
    const ushort_t* __restrict__ A, const ushort_t* __restrict__ Bt,
    void* __restrict__ Cv, int M, int N, int K)
{
    __shared__ ushort_t As[128 * 64];
    __shared__ ushort_t Bs[128 * 64];
    const int t     = threadIdx.x;
    const int bm    = blockIdx.y * 128;
    const int bn    = blockIdx.x * 128;
    const int lane  = t & 63;
    const int w     = t >> 6;
    const int wr    = w >> 1, wc = w & 1;           // wave -> 64x64 sub-tile
    const int row16 = lane & 15;
    const int khalf = lane >> 4;                    // 0..3

    f32x4 acc[4][4] = {};

    // staging: thread t copies 16B: row = i*32 + t/8, col elems = (t&7)*8
    const int srow = t >> 3;
    const int scol = (t & 7) * 8;
    const ushort_t* ga = A  + (size_t)(bm + srow) * K + scol;
    const ushort_t* gb = Bt + (size_t)(bn + srow) * K + scol;
    ushort_t* la = &As[srow * 64 + scol];
    ushort_t* lb = &Bs[srow * 64 + scol];
    const size_t rowstep = (size_t)32 * K;

    const int kIters = K >> 6;
    for (int it = 0; it < kIters; ++it) {
        const int k0 = it << 6;
#pragma unroll
        for (int i = 0; i < 4; ++i) {
            gload_lds16(ga + i * rowstep + k0, la + i * 32 * 64);
            gload_lds16(gb + i * rowstep + k0, lb + i * 32 * 64);
        }
        __syncthreads();   // drains vmcnt before barrier (compiler-emitted)
#pragma unroll
        for (int kk = 0; kk < 2; ++kk) {
            short8 af[4], bfr[4];
#pragma unroll
            for (int mi = 0; mi < 4; ++mi)
                af[mi] = *(const short8*)&As[(wr * 64 + mi * 16 + row16) * 64 + kk * 32 + khalf * 8];
#pragma unroll
            for (int ni = 0; ni < 4; ++ni)
                bfr[ni] = *(const short8*)&Bs[(wc * 64 + ni * 16 + row16) * 64 + kk * 32 + khalf * 8];
#pragma unroll
            for (int mi = 0; mi < 4; ++mi)
#pragma unroll
                for (int ni = 0; ni < 4; ++ni)
                    acc[mi][ni] = __builtin_amdgcn_mfma_f32_16x16x32_bf16(
                        af[mi], bfr[ni], acc[mi][ni], 0, 0, 0);
        }
        __syncthreads();
    }

    // epilogue: C row = (lane>>4)*4 + reg, col = lane&15  [m89-verified]
    const int r0 = bm + wr * 64 + khalf * 4;
    const int c0 = bn + wc * 64 + row16;
#pragma unroll
    for (int mi = 0; mi < 4; ++mi)
#pragma unroll
        for (int ni = 0; ni < 4; ++ni)
#pragma unroll
            for (int j = 0; j < 4; ++j) {
                const size_t idx = (size_t)(r0 + mi * 16 + j) * N + (c0 + ni * 16);
                if (OUT_BF16) ((ushort_t*)Cv)[idx] = f2bf(acc[mi][ni][j]);
                else          ((float*)Cv)[idx]    = acc[mi][ni][j];
            }
}

// ---------------------------------------------------------------------------
// Attention over G=18 connections. One block per token m, 512 threads =
// 8 waves = 8 heads; lane = d. Softmax in f32, wave shfl-xor reduce over D=64.
// ---------------------------------------------------------------------------
__global__ __launch_bounds__(512) void attention_kernel(
    const ushort_t* __restrict__ Q, const ushort_t* __restrict__ KV,
    ushort_t* __restrict__ Ao)
{
    const int m = blockIdx.x;
    const int t = threadIdx.x;
    const int n = t >> 6;       // head
    const int d = t & 63;
    const size_t qoff = (size_t)m * H_ + n * D_ + d;
    const float q = bf2f(Q[qoff]);
    const size_t kvbase = (size_t)m * NBIG;

    float s[G_];
#pragma unroll
    for (int g = 0; g < G_; ++g) {
        float kd = bf2f(KV[kvbase + (size_t)g * H_ + n * D_ + d]);
        float p = q * kd;
#pragma unroll
        for (int off = 32; off >= 1; off >>= 1) p += __shfl_xor(p, off);
        s[g] = p * 0.125f;                          // 1/sqrt(64)
    }
    float mx = s[0];
#pragma unroll
    for (int g = 1; g < G_; ++g) mx = fmaxf(mx, s[g]);
    float sum = 0.f;
#pragma unroll
    for (int g = 0; g < G_; ++g) { s[g] = __expf(s[g] - mx); sum += s[g]; }
    const float inv = 1.0f / sum;

    float out = 0.f;
#pragma unroll
    for (int g = 0; g < G_; ++g) {
        float vd = bf2f(KV[kvbase + KBIG + (size_t)g * H_ + n * D_ + d]);
        out += s[g] * vd;
    }
    Ao[qoff] = f2bf(out * inv);
}

// ---------------------------------------------------------------------------
extern "C" void kernel_launch(void* const* d_in, const int* in_sizes, int n_in,
                              void* d_out, int out_size, void* d_ws, size_t ws_size,
                              hipStream_t stream)
{
    const float* hs   = (const float*)d_in[0];
    const int*   conn = (const int*)d_in[1];
    const float* Wq   = (const float*)d_in[2];
    const float* Wk   = (const float*)d_in[3];
    const float* Wv   = (const float*)d_in[4];
    const float* Wo   = (const float*)d_in[5];
    float* out = (float*)d_out;

    // workspace carve-up (total ~819 MB)
    char* ws = (char*)d_ws;
    ushort_t* Wt  = (ushort_t*)ws;  ws += (size_t)NBIG * KBIG * 2;  // 339.7 MB [N][K]
    ushort_t* Wqt = (ushort_t*)ws;  ws += (size_t)H_ * H_ * 2;
    ushort_t* Wot = (ushort_t*)ws;  ws += (size_t)H_ * H_ * 2;
    ushort_t* hsb = (ushort_t*)ws;  ws += (size_t)M_ * H_ * 2;
    ushort_t* Ab  = (ushort_t*)ws;  ws += (size_t)M_ * KBIG * 2;    // 151 MB
    ushort_t* Qb  = (ushort_t*)ws;  ws += (size_t)M_ * H_ * 2;
    ushort_t* KVb = (ushort_t*)ws;  ws += (size_t)M_ * NBIG * 2;    // 302 MB
    ushort_t* Aob = (ushort_t*)ws;  ws += (size_t)M_ * H_ * 2;

    // 1. weights -> bf16, transposed to [N][K]
    transpose_f32_to_bf16<<<dim3(KBIG / 64, KBIG / 64), 256, 0, stream>>>(Wk, Wt, KBIG, KBIG);
    transpose_f32_to_bf16<<<dim3(KBIG / 64, KBIG / 64), 256, 0, stream>>>(Wv, Wt + (size_t)KBIG * KBIG, KBIG, KBIG);
    transpose_f32_to_bf16<<<dim3(H_ / 64, H_ / 64), 256, 0, stream>>>(Wq, Wqt, H_, H_);
    transpose_f32_to_bf16<<<dim3(H_ / 64, H_ / 64), 256, 0, stream>>>(Wo, Wot, H_, H_);

    // 2. hidden_states -> bf16
    convert_f32_bf16<<<(M_ * H_ / 4 + 255) / 256, 256, 0, stream>>>(hs, hsb, M_ * H_ / 4);

    // 3. gathered A matrix (connections -> rows of hs, bf16)
    build_A<<<dim3(G_, M_), 256, 0, stream>>>(hs, conn, Ab);

    // 4. Q = hs @ Wq           [8192,512]x[512,512]
    gemm_bf16_nt<1><<<dim3(H_ / 128, M_ / 128), 256, 0, stream>>>(hsb, Wqt, Qb, M_, H_, H_);

    // 5. KV = A @ [Wk|Wv]      [8192,9216]x[9216,18432]  — the 2.78 TFLOP GEMM
    gemm_bf16_nt<1><<<dim3(NBIG / 128, M_ / 128), 256, 0, stream>>>(Ab, Wt, KVb, M_, NBIG, KBIG);

    // 6. selective attention (softmax over G per head)
    attention_kernel<<<M_, 512, 0, stream>>>(Qb, KVb, Aob);

    // 7. out = attn_out @ Wo   [8192,512]x[512,512], f32 output
    gemm_bf16_nt<0><<<dim3(H_ / 128, M_ / 128), 256, 0, stream>>>(Aob, Wot, out, M_, H_, H_);
}